// Round 3
// baseline (355.963 us; speedup 1.0000x reference)
//
#include <hip/hip_runtime.h>

#define BATCH 4096
#define ISZ   1024
#define HSZ   2048

typedef __bf16 bf16x8 __attribute__((ext_vector_type(8)));
typedef float  f32x4  __attribute__((ext_vector_type(4)));

// ---------- fp32 <-> bf16 ----------
__device__ __forceinline__ unsigned short f2bf(float f) {
  unsigned u = __builtin_bit_cast(unsigned, f);
  u += 0x7fffu + ((u >> 16) & 1u);
  return (unsigned short)(u >> 16);
}
__device__ __forceinline__ float bf2f(unsigned short s) {
  unsigned u = ((unsigned)s) << 16;
  return __builtin_bit_cast(float, u);
}

// ---------- cvt1: the 6 tensors gate_rz depends on ----------
struct CvtArgs {
  const float* src[6];
  unsigned short* dst[6];
  int cum[7];   // prefix sums of float4 counts
};

__global__ __launch_bounds__(256) void cvt_all_kernel(CvtArgs a, int total4) {
  int i = blockIdx.x * 256 + threadIdx.x;
  if (i >= total4) return;
  int s = 0;
#pragma unroll
  for (int k = 0; k < 5; ++k) s += (i >= a.cum[k + 1]) ? 1 : 0;
  int off = i - a.cum[s];
  float4 f = ((const float4*)a.src[s])[off];
  ushort4 o;
  o.x = f2bf(f.x); o.y = f2bf(f.y); o.z = f2bf(f.z); o.w = f2bf(f.w);
  ((ushort4*)a.dst[s])[off] = o;
}

// ---------- staging: BK=64, XOR-8 swizzled LDS (conflict-free, verified) ----------
// 128-row tile, 256-thread block: 1024 16-B chunks, 4/thread.
__device__ __forceinline__ void stage_tile64(const unsigned short* __restrict__ g, int ldK,
                                             int tileRow, int k0, char* lds, int t) {
  char* l0 = lds + ((t >> 6) << 10);  // wave-uniform base
#pragma unroll
  for (int k = 0; k < 4; ++k) {
    int linear = t + k * 256;        // chunk id, 0..1023
    int row = linear >> 3;           // 0..127
    int cs  = linear & 7;
    int c   = cs ^ (row & 7);        // XOR swizzle on global side
    const unsigned short* gp = g + (size_t)(tileRow + row) * ldK + (k0 + c * 8);
    __builtin_amdgcn_global_load_lds((const __attribute__((address_space(1))) void*)gp,
                                     (__attribute__((address_space(3))) void*)(l0 + k * 4096),
                                     16, 0, 0);
  }
}

// ---------- dual-B 128x(2x128) GEMM segment, 4 waves ----------
// Shared A-tile, two B-tiles, dual accumulators. Used for merged R+Z (two gates,
// same cols) AND for gate_h (one gate, two adjacent 128-col panels: pass
// B2 = B1 + 128*ldK).
__device__ __forceinline__ void gemm_seg_rz(const unsigned short* __restrict__ A,
                                            const unsigned short* __restrict__ Br,
                                            const unsigned short* __restrict__ Bz,
                                            int K, int rowBase, int colBase,
                                            char* ldsA, char* ldsBr, char* ldsBz,
                                            f32x4 (&accR)[4][4], f32x4 (&accZ)[4][4], int t) {
  const int lane = t & 63;
  const int wid  = t >> 6;
  const int wm   = wid >> 1, wn = wid & 1;
  const int lrow = lane & 15;
  const int quad = lane >> 4;
  const int r7   = lrow & 7;
  for (int k0 = 0; k0 < K; k0 += 64) {
    stage_tile64(A,  K, rowBase, k0, ldsA,  t);
    stage_tile64(Br, K, colBase, k0, ldsBr, t);
    stage_tile64(Bz, K, colBase, k0, ldsBz, t);
    __syncthreads();
#pragma unroll
    for (int kk = 0; kk < 2; ++kk) {
      const int swz = (((kk << 2) | quad) ^ r7) * 16;
      bf16x8 af[4], bfr[4];
#pragma unroll
      for (int i = 0; i < 4; ++i)
        af[i] = *(const bf16x8*)(ldsA + (wm * 64 + i * 16 + lrow) * 128 + swz);
      // panel 1
#pragma unroll
      for (int j = 0; j < 4; ++j)
        bfr[j] = *(const bf16x8*)(ldsBr + (wn * 64 + j * 16 + lrow) * 128 + swz);
#pragma unroll
      for (int i = 0; i < 4; ++i)
#pragma unroll
        for (int j = 0; j < 4; ++j)
          accR[i][j] = __builtin_amdgcn_mfma_f32_16x16x32_bf16(af[i], bfr[j], accR[i][j], 0, 0, 0);
      // panel 2 (reuse bfr registers)
#pragma unroll
      for (int j = 0; j < 4; ++j)
        bfr[j] = *(const bf16x8*)(ldsBz + (wn * 64 + j * 16 + lrow) * 128 + swz);
#pragma unroll
      for (int i = 0; i < 4; ++i)
#pragma unroll
        for (int j = 0; j < 4; ++j)
          accZ[i][j] = __builtin_amdgcn_mfma_f32_16x16x32_bf16(af[i], bfr[j], accZ[i][j], 0, 0, 0);
    }
    __syncthreads();
  }
}

__device__ __forceinline__ float fast_sigmoid(float v) {
  return 1.0f / (1.0f + __expf(-v));
}
__device__ __forceinline__ float fast_tanh(float v) {
  float e = __expf(2.0f * v);
  return 1.0f - 2.0f / (e + 1.0f);   // safe at +/-inf
}

// ---------- Kernel A: z==0 plane converts Wh/Uh (overlapped); z==1 merged R+Z ----------
__global__ __launch_bounds__(256, 2) void gate_rz(
    const unsigned short* __restrict__ xb, const unsigned short* __restrict__ hb,
    const unsigned short* __restrict__ Wr, const unsigned short* __restrict__ Ur,
    const unsigned short* __restrict__ Wz, const unsigned short* __restrict__ Uz,
    const float* __restrict__ br, const float* __restrict__ bz,
    const float* __restrict__ Wh32, const float* __restrict__ Uh32,
    unsigned short* __restrict__ Whb, unsigned short* __restrict__ Uhb,
    unsigned short* __restrict__ rh, unsigned short* __restrict__ Zbuf) {
  __shared__ char lds[49152];
  const int t = threadIdx.x;

  if (blockIdx.z == 0) {
    // dispatched first (z-major last): converts Wh+Uh during gate_rz's first wave
    const int NW = (HSZ * ISZ) / 4;          // 524288 float4 in Wh
    const int NU = (HSZ * HSZ) / 4;          // 1048576 float4 in Uh
    int tid = (blockIdx.x + (blockIdx.y << 4)) * 256 + t;   // 0..131071
    for (int i = tid; i < NW + NU; i += 512 * 256) {
      const float4* s4 = (i < NW) ? (const float4*)Wh32 + i
                                  : (const float4*)Uh32 + (i - NW);
      ushort4* d4 = (i < NW) ? (ushort4*)Whb + i
                             : (ushort4*)Uhb + (i - NW);
      float4 f = *s4;
      ushort4 o;
      o.x = f2bf(f.x); o.y = f2bf(f.y); o.z = f2bf(f.z); o.w = f2bf(f.w);
      *d4 = o;
    }
    return;
  }

  char* ldsA  = lds;
  char* ldsBr = lds + 16384;
  char* ldsBz = lds + 32768;

  // weight-stationary XCD swizzle over the 512 merged blocks:
  // each XCD owns 2 col-panels -> Wr/Wz/Ur/Uz panel set = 3 MiB, L2-resident.
  int lin = blockIdx.x + (blockIdx.y << 4);
  int xcd = lin & 7, s = lin >> 3;
  int bx = xcd * 2 + (s & 1);
  int by = s >> 1;                  // 0..31

  const int rowBase = by * 128;
  const int colBase = bx * 128;

  f32x4 accR[4][4], accZ[4][4];
#pragma unroll
  for (int i = 0; i < 4; ++i)
#pragma unroll
    for (int j = 0; j < 4; ++j) {
      accR[i][j] = (f32x4){0.f, 0.f, 0.f, 0.f};
      accZ[i][j] = (f32x4){0.f, 0.f, 0.f, 0.f};
    }

  gemm_seg_rz(xb, Wr, Wz, ISZ, rowBase, colBase, ldsA, ldsBr, ldsBz, accR, accZ, t);
  gemm_seg_rz(hb, Ur, Uz, HSZ, rowBase, colBase, ldsA, ldsBr, ldsBz, accR, accZ, t);

  const int lane = t & 63, wid = t >> 6;
  const int wm = wid >> 1, wn = wid & 1, lrow = lane & 15, quad = lane >> 4;
#pragma unroll
  for (int i = 0; i < 4; ++i) {
#pragma unroll
    for (int j = 0; j < 4; ++j) {
      int col = colBase + wn * 64 + j * 16 + lrow;
      float bvr = br[col];
      float bvz = bz[col];
#pragma unroll
      for (int r = 0; r < 4; ++r) {
        int row = rowBase + wm * 64 + i * 16 + quad * 4 + r;
        int idx = row * HSZ + col;
        float hv = bf2f(hb[idx]);
        float sr = fast_sigmoid(accR[i][j][r] + bvr);
        float sz = fast_sigmoid(accZ[i][j][r] + bvz);
        rh[idx]   = f2bf(sr * hv);
        Zbuf[idx] = f2bf(sz);
      }
    }
  }
}

// ---------- Kernel B: 128x256 tile via dual col-panels, 4 waves (clone of RZ structure) ----------
__global__ __launch_bounds__(256, 2) void gate_h(
    const unsigned short* __restrict__ xb, const unsigned short* __restrict__ rhb,
    const unsigned short* __restrict__ Wh, const unsigned short* __restrict__ Uh,
    const float* __restrict__ bh, const unsigned short* __restrict__ Zbuf,
    const float* __restrict__ hprev, float* __restrict__ out) {
  __shared__ char lds[49152];
  char* ldsA  = lds;
  char* ldsB0 = lds + 16384;
  char* ldsB1 = lds + 32768;
  const int t = threadIdx.x;

  // weight-stationary: col-panel (256 wide) == XCD; Wh/Uh panel = 1.5 MiB, L2-resident.
  // grid (8, 32): blockIdx.x = col-panel, blockIdx.y = row-panel.
  const int colBase = blockIdx.x * 256;
  const int rowBase = blockIdx.y * 128;

  f32x4 accL[4][4], accR2[4][4];
#pragma unroll
  for (int i = 0; i < 4; ++i)
#pragma unroll
    for (int j = 0; j < 4; ++j) {
      accL[i][j]  = (f32x4){0.f, 0.f, 0.f, 0.f};
      accR2[i][j] = (f32x4){0.f, 0.f, 0.f, 0.f};
    }

  // panel 2 = same weights, rows +128: pointer advanced 128*ldK
  gemm_seg_rz(xb,  Wh, Wh + (size_t)128 * ISZ, ISZ, rowBase, colBase,
              ldsA, ldsB0, ldsB1, accL, accR2, t);
  gemm_seg_rz(rhb, Uh, Uh + (size_t)128 * HSZ, HSZ, rowBase, colBase,
              ldsA, ldsB0, ldsB1, accL, accR2, t);

  const int lane = t & 63, wid = t >> 6;
  const int wm = wid >> 1, wn = wid & 1, lrow = lane & 15, quad = lane >> 4;

  auto epi = [&](f32x4 (&acc)[4][4], int colOff) {
#pragma unroll
    for (int i = 0; i < 4; ++i) {
#pragma unroll
      for (int j = 0; j < 4; ++j) {
        int col = colBase + colOff + wn * 64 + j * 16 + lrow;
        float bv = bh[col];
#pragma unroll
        for (int r = 0; r < 4; ++r) {
          int row = rowBase + wm * 64 + i * 16 + quad * 4 + r;
          float hp = fast_tanh(acc[i][j][r] + bv);
          int idx = row * HSZ + col;
          float z = bf2f(Zbuf[idx]);
          float h = hprev[idx];
          out[idx] = h + z * (hp - h);
        }
      }
    }
  };
  epi(accL, 0);
  epi(accR2, 128);
}

// ---------- host ----------
extern "C" void kernel_launch(void* const* d_in, const int* in_sizes, int n_in,
                              void* d_out, int out_size, void* d_ws, size_t ws_size,
                              hipStream_t stream) {
  (void)in_sizes; (void)n_in; (void)out_size; (void)ws_size;
  const float* x     = (const float*)d_in[0];
  const float* hprev = (const float*)d_in[1];
  const float* Wh    = (const float*)d_in[2];
  const float* Wz    = (const float*)d_in[3];
  const float* Wr    = (const float*)d_in[4];
  const float* Uh    = (const float*)d_in[5];
  const float* Uz    = (const float*)d_in[6];
  const float* Ur    = (const float*)d_in[7];
  const float* bh    = (const float*)d_in[8];
  const float* bz    = (const float*)d_in[9];
  const float* br    = (const float*)d_in[10];
  float* out = (float*)d_out;

  char* ws = (char*)d_ws;
  size_t off = 0;
  auto alloc = [&](size_t bytes) { char* p = ws + off; off += bytes; return p; };
  unsigned short* xb  = (unsigned short*)alloc((size_t)BATCH * ISZ * 2);
  unsigned short* hb  = (unsigned short*)alloc((size_t)BATCH * HSZ * 2);
  unsigned short* Wrb = (unsigned short*)alloc((size_t)HSZ * ISZ * 2);
  unsigned short* Wzb = (unsigned short*)alloc((size_t)HSZ * ISZ * 2);
  unsigned short* Whb = (unsigned short*)alloc((size_t)HSZ * ISZ * 2);
  unsigned short* Urb = (unsigned short*)alloc((size_t)HSZ * HSZ * 2);
  unsigned short* Uzb = (unsigned short*)alloc((size_t)HSZ * HSZ * 2);
  unsigned short* Uhb = (unsigned short*)alloc((size_t)HSZ * HSZ * 2);
  unsigned short* rhb = (unsigned short*)alloc((size_t)BATCH * HSZ * 2);
  unsigned short* Zb  = (unsigned short*)alloc((size_t)BATCH * HSZ * 2);

  // cvt1: only what gate_rz needs (Wh/Uh are converted inside gate_rz's z==0 plane)
  CvtArgs ca;
  const float* srcs[6]      = {x, hprev, Wr, Wz, Ur, Uz};
  unsigned short* dsts[6]   = {xb, hb, Wrb, Wzb, Urb, Uzb};
  int n4s[6] = {BATCH * ISZ / 4, BATCH * HSZ / 4,
                HSZ * ISZ / 4, HSZ * ISZ / 4,
                HSZ * HSZ / 4, HSZ * HSZ / 4};
  int cum = 0;
  for (int i = 0; i < 6; ++i) {
    ca.src[i] = srcs[i];
    ca.dst[i] = dsts[i];
    ca.cum[i] = cum;
    cum += n4s[i];
  }
  ca.cum[6] = cum;
  cvt_all_kernel<<<(cum + 255) / 256, 256, 0, stream>>>(ca, cum);

  dim3 gridA(HSZ / 128, BATCH / 128, 2);   // z=0: Wh/Uh cvt plane; z=1: merged R+Z gemm
  gate_rz<<<gridA, 256, 0, stream>>>(xb, hb, Wrb, Urb, Wzb, Uzb, br, bz,
                                     Wh, Uh, Whb, Uhb, rhb, Zb);

  dim3 gridB(8, BATCH / 128, 1);           // 256 blocks: 8 col-panels x 32 row-panels
  gate_h<<<gridB, 256, 0, stream>>>(xb, rhb, Whb, Uhb, bh, Zb, hprev, out);
}

// Round 4
// 340.375 us; speedup vs baseline: 1.0458x; 1.0458x over previous
//
#include <hip/hip_runtime.h>

#define BATCH 4096
#define ISZ   1024
#define HSZ   2048

typedef __bf16 bf16x8 __attribute__((ext_vector_type(8)));
typedef float  f32x4  __attribute__((ext_vector_type(4)));

// ---------- fp32 <-> bf16 ----------
__device__ __forceinline__ unsigned short f2bf(float f) {
  unsigned u = __builtin_bit_cast(unsigned, f);
  u += 0x7fffu + ((u >> 16) & 1u);
  return (unsigned short)(u >> 16);
}
__device__ __forceinline__ float bf2f(unsigned short s) {
  unsigned u = ((unsigned)s) << 16;
  return __builtin_bit_cast(float, u);
}

// ---------- cvt1: the 6 tensors gate_rz depends on ----------
struct CvtArgs {
  const float* src[6];
  unsigned short* dst[6];
  int cum[7];   // prefix sums of float4 counts
};

__global__ __launch_bounds__(256) void cvt_all_kernel(CvtArgs a, int total4) {
  int i = blockIdx.x * 256 + threadIdx.x;
  if (i >= total4) return;
  int s = 0;
#pragma unroll
  for (int k = 0; k < 5; ++k) s += (i >= a.cum[k + 1]) ? 1 : 0;
  int off = i - a.cum[s];
  float4 f = ((const float4*)a.src[s])[off];
  ushort4 o;
  o.x = f2bf(f.x); o.y = f2bf(f.y); o.z = f2bf(f.z); o.w = f2bf(f.w);
  ((ushort4*)a.dst[s])[off] = o;
}

// ---------- staging: BK=64, XOR-8 swizzled LDS (conflict-free, verified) ----------
// 128-row tile, 256-thread block: 1024 16-B chunks, 4/thread.
__device__ __forceinline__ void stage_tile64(const unsigned short* __restrict__ g, int ldK,
                                             int tileRow, int k0, char* lds, int t) {
  char* l0 = lds + ((t >> 6) << 10);  // wave-uniform base
#pragma unroll
  for (int k = 0; k < 4; ++k) {
    int linear = t + k * 256;        // chunk id, 0..1023
    int row = linear >> 3;           // 0..127
    int cs  = linear & 7;
    int c   = cs ^ (row & 7);        // XOR swizzle on global side
    const unsigned short* gp = g + (size_t)(tileRow + row) * ldK + (k0 + c * 8);
    __builtin_amdgcn_global_load_lds((const __attribute__((address_space(1))) void*)gp,
                                     (__attribute__((address_space(3))) void*)(l0 + k * 4096),
                                     16, 0, 0);
  }
}

// ---------- dual-B 128x(2x128) GEMM segment, 4 waves (merged R+Z; verified 966 TF) ----------
__device__ __forceinline__ void gemm_seg_rz(const unsigned short* __restrict__ A,
                                            const unsigned short* __restrict__ Br,
                                            const unsigned short* __restrict__ Bz,
                                            int K, int rowBase, int colBase,
                                            char* ldsA, char* ldsBr, char* ldsBz,
                                            f32x4 (&accR)[4][4], f32x4 (&accZ)[4][4], int t) {
  const int lane = t & 63;
  const int wid  = t >> 6;
  const int wm   = wid >> 1, wn = wid & 1;
  const int lrow = lane & 15;
  const int quad = lane >> 4;
  const int r7   = lrow & 7;
  for (int k0 = 0; k0 < K; k0 += 64) {
    stage_tile64(A,  K, rowBase, k0, ldsA,  t);
    stage_tile64(Br, K, colBase, k0, ldsBr, t);
    stage_tile64(Bz, K, colBase, k0, ldsBz, t);
    __syncthreads();
#pragma unroll
    for (int kk = 0; kk < 2; ++kk) {
      const int swz = (((kk << 2) | quad) ^ r7) * 16;
      bf16x8 af[4], bfr[4];
#pragma unroll
      for (int i = 0; i < 4; ++i)
        af[i] = *(const bf16x8*)(ldsA + (wm * 64 + i * 16 + lrow) * 128 + swz);
#pragma unroll
      for (int j = 0; j < 4; ++j)
        bfr[j] = *(const bf16x8*)(ldsBr + (wn * 64 + j * 16 + lrow) * 128 + swz);
#pragma unroll
      for (int i = 0; i < 4; ++i)
#pragma unroll
        for (int j = 0; j < 4; ++j)
          accR[i][j] = __builtin_amdgcn_mfma_f32_16x16x32_bf16(af[i], bfr[j], accR[i][j], 0, 0, 0);
#pragma unroll
      for (int j = 0; j < 4; ++j)
        bfr[j] = *(const bf16x8*)(ldsBz + (wn * 64 + j * 16 + lrow) * 128 + swz);
#pragma unroll
      for (int i = 0; i < 4; ++i)
#pragma unroll
        for (int j = 0; j < 4; ++j)
          accZ[i][j] = __builtin_amdgcn_mfma_f32_16x16x32_bf16(af[i], bfr[j], accZ[i][j], 0, 0, 0);
    }
    __syncthreads();
  }
}

// ---------- single-B 128x128 GEMM segment, 4 waves (verified 937 TF, round-0 code) ----------
__device__ __forceinline__ void gemm_seg(const unsigned short* __restrict__ A,
                                         const unsigned short* __restrict__ W,
                                         int K, int rowBase, int colBase,
                                         char* ldsA, char* ldsB,
                                         f32x4 (&acc)[4][4], int t) {
  const int lane = t & 63;
  const int wid  = t >> 6;
  const int wm   = wid >> 1, wn = wid & 1;
  const int lrow = lane & 15;
  const int quad = lane >> 4;
  const int r7   = lrow & 7;
  for (int k0 = 0; k0 < K; k0 += 64) {
    stage_tile64(A, K, rowBase, k0, ldsA, t);
    stage_tile64(W, K, colBase, k0, ldsB, t);
    __syncthreads();
#pragma unroll
    for (int kk = 0; kk < 2; ++kk) {
      const int swz = (((kk << 2) | quad) ^ r7) * 16;
      bf16x8 af[4], bfr[4];
#pragma unroll
      for (int i = 0; i < 4; ++i) {
        af[i]  = *(const bf16x8*)(ldsA + (wm * 64 + i * 16 + lrow) * 128 + swz);
        bfr[i] = *(const bf16x8*)(ldsB + (wn * 64 + i * 16 + lrow) * 128 + swz);
      }
#pragma unroll
      for (int i = 0; i < 4; ++i)
#pragma unroll
        for (int j = 0; j < 4; ++j)
          acc[i][j] = __builtin_amdgcn_mfma_f32_16x16x32_bf16(af[i], bfr[j], acc[i][j], 0, 0, 0);
    }
    __syncthreads();
  }
}

__device__ __forceinline__ float fast_sigmoid(float v) {
  return 1.0f / (1.0f + __expf(-v));
}
__device__ __forceinline__ float fast_tanh(float v) {
  float e = __expf(2.0f * v);
  return 1.0f - 2.0f / (e + 1.0f);   // safe at +/-inf
}

// ---------- Kernel A: z==0 plane converts Wh/Uh (overlapped); z==1 merged R+Z ----------
__global__ __launch_bounds__(256, 2) void gate_rz(
    const unsigned short* __restrict__ xb, const unsigned short* __restrict__ hb,
    const unsigned short* __restrict__ Wr, const unsigned short* __restrict__ Ur,
    const unsigned short* __restrict__ Wz, const unsigned short* __restrict__ Uz,
    const float* __restrict__ br, const float* __restrict__ bz,
    const float* __restrict__ Wh32, const float* __restrict__ Uh32,
    unsigned short* __restrict__ Whb, unsigned short* __restrict__ Uhb,
    unsigned short* __restrict__ rh, unsigned short* __restrict__ Zbuf) {
  __shared__ char lds[49152];
  const int t = threadIdx.x;

  if (blockIdx.z == 0) {
    // dispatched first (z-major last): converts Wh+Uh during gate_rz's first wave
    const int NW = (HSZ * ISZ) / 4;          // 524288 float4 in Wh
    const int NU = (HSZ * HSZ) / 4;          // 1048576 float4 in Uh
    int tid = (blockIdx.x + (blockIdx.y << 4)) * 256 + t;   // 0..131071
    for (int i = tid; i < NW + NU; i += 512 * 256) {
      const float4* s4 = (i < NW) ? (const float4*)Wh32 + i
                                  : (const float4*)Uh32 + (i - NW);
      ushort4* d4 = (i < NW) ? (ushort4*)Whb + i
                             : (ushort4*)Uhb + (i - NW);
      float4 f = *s4;
      ushort4 o;
      o.x = f2bf(f.x); o.y = f2bf(f.y); o.z = f2bf(f.z); o.w = f2bf(f.w);
      *d4 = o;
    }
    return;
  }

  char* ldsA  = lds;
  char* ldsBr = lds + 16384;
  char* ldsBz = lds + 32768;

  // weight-stationary XCD swizzle over the 512 merged blocks:
  // each XCD owns 2 col-panels -> Wr/Wz/Ur/Uz panel set = 3 MiB, L2-resident.
  int lin = blockIdx.x + (blockIdx.y << 4);
  int xcd = lin & 7, s = lin >> 3;
  int bx = xcd * 2 + (s & 1);
  int by = s >> 1;                  // 0..31

  const int rowBase = by * 128;
  const int colBase = bx * 128;

  f32x4 accR[4][4], accZ[4][4];
#pragma unroll
  for (int i = 0; i < 4; ++i)
#pragma unroll
    for (int j = 0; j < 4; ++j) {
      accR[i][j] = (f32x4){0.f, 0.f, 0.f, 0.f};
      accZ[i][j] = (f32x4){0.f, 0.f, 0.f, 0.f};
    }

  gemm_seg_rz(xb, Wr, Wz, ISZ, rowBase, colBase, ldsA, ldsBr, ldsBz, accR, accZ, t);
  gemm_seg_rz(hb, Ur, Uz, HSZ, rowBase, colBase, ldsA, ldsBr, ldsBz, accR, accZ, t);

  const int lane = t & 63, wid = t >> 6;
  const int wm = wid >> 1, wn = wid & 1, lrow = lane & 15, quad = lane >> 4;
#pragma unroll
  for (int i = 0; i < 4; ++i) {
#pragma unroll
    for (int j = 0; j < 4; ++j) {
      int col = colBase + wn * 64 + j * 16 + lrow;
      float bvr = br[col];
      float bvz = bz[col];
#pragma unroll
      for (int r = 0; r < 4; ++r) {
        int row = rowBase + wm * 64 + i * 16 + quad * 4 + r;
        int idx = row * HSZ + col;
        float hv = bf2f(hb[idx]);
        float sr = fast_sigmoid(accR[i][j][r] + bvr);
        float sz = fast_sigmoid(accZ[i][j][r] + bvz);
        rh[idx]   = f2bf(sr * hv);
        Zbuf[idx] = f2bf(sz);
      }
    }
  }
}

// ---------- Kernel B: 128x128 tile, 4 waves, 512 blocks (m97-shape, 4 blocks/CU) ----------
__global__ __launch_bounds__(256, 4) void gate_h(
    const unsigned short* __restrict__ xb, const unsigned short* __restrict__ rhb,
    const unsigned short* __restrict__ Wh, const unsigned short* __restrict__ Uh,
    const float* __restrict__ bh, const unsigned short* __restrict__ Zbuf,
    const float* __restrict__ hprev, float* __restrict__ out) {
  __shared__ char lds[32768];
  char* ldsA = lds;
  char* ldsB = lds + 16384;
  const int t = threadIdx.x;

  // weight-stationary XCD swizzle: each XCD owns 2 column-panels (grid 16x32)
  int lin = blockIdx.x + (blockIdx.y << 4);
  int xcd = lin & 7, s = lin >> 3;
  int bx = xcd * 2 + (s & 1);
  int by = s >> 1;

  const int rowBase = by * 128;
  const int colBase = bx * 128;

  f32x4 acc[4][4];
#pragma unroll
  for (int i = 0; i < 4; ++i)
#pragma unroll
    for (int j = 0; j < 4; ++j)
      acc[i][j] = (f32x4){0.f, 0.f, 0.f, 0.f};

  gemm_seg(xb,  Wh, ISZ, rowBase, colBase, ldsA, ldsB, acc, t);
  gemm_seg(rhb, Uh, HSZ, rowBase, colBase, ldsA, ldsB, acc, t);

  const int lane = t & 63, wid = t >> 6;
  const int wm = wid >> 1, wn = wid & 1, lrow = lane & 15, quad = lane >> 4;
#pragma unroll
  for (int i = 0; i < 4; ++i) {
#pragma unroll
    for (int j = 0; j < 4; ++j) {
      int col = colBase + wn * 64 + j * 16 + lrow;
      float bv = bh[col];
#pragma unroll
      for (int r = 0; r < 4; ++r) {
        int row = rowBase + wm * 64 + i * 16 + quad * 4 + r;
        float hp = fast_tanh(acc[i][j][r] + bv);
        int idx = row * HSZ + col;
        float z = bf2f(Zbuf[idx]);
        float h = hprev[idx];
        out[idx] = h + z * (hp - h);
      }
    }
  }
}

// ---------- host ----------
extern "C" void kernel_launch(void* const* d_in, const int* in_sizes, int n_in,
                              void* d_out, int out_size, void* d_ws, size_t ws_size,
                              hipStream_t stream) {
  (void)in_sizes; (void)n_in; (void)out_size; (void)ws_size;
  const float* x     = (const float*)d_in[0];
  const float* hprev = (const float*)d_in[1];
  const float* Wh    = (const float*)d_in[2];
  const float* Wz    = (const float*)d_in[3];
  const float* Wr    = (const float*)d_in[4];
  const float* Uh    = (const float*)d_in[5];
  const float* Uz    = (const float*)d_in[6];
  const float* Ur    = (const float*)d_in[7];
  const float* bh    = (const float*)d_in[8];
  const float* bz    = (const float*)d_in[9];
  const float* br    = (const float*)d_in[10];
  float* out = (float*)d_out;

  char* ws = (char*)d_ws;
  size_t off = 0;
  auto alloc = [&](size_t bytes) { char* p = ws + off; off += bytes; return p; };
  unsigned short* xb  = (unsigned short*)alloc((size_t)BATCH * ISZ * 2);
  unsigned short* hb  = (unsigned short*)alloc((size_t)BATCH * HSZ * 2);
  unsigned short* Wrb = (unsigned short*)alloc((size_t)HSZ * ISZ * 2);
  unsigned short* Wzb = (unsigned short*)alloc((size_t)HSZ * ISZ * 2);
  unsigned short* Whb = (unsigned short*)alloc((size_t)HSZ * ISZ * 2);
  unsigned short* Urb = (unsigned short*)alloc((size_t)HSZ * HSZ * 2);
  unsigned short* Uzb = (unsigned short*)alloc((size_t)HSZ * HSZ * 2);
  unsigned short* Uhb = (unsigned short*)alloc((size_t)HSZ * HSZ * 2);
  unsigned short* rhb = (unsigned short*)alloc((size_t)BATCH * HSZ * 2);
  unsigned short* Zb  = (unsigned short*)alloc((size_t)BATCH * HSZ * 2);

  // cvt1: only what gate_rz needs (Wh/Uh are converted inside gate_rz's z==0 plane)
  CvtArgs ca;
  const float* srcs[6]      = {x, hprev, Wr, Wz, Ur, Uz};
  unsigned short* dsts[6]   = {xb, hb, Wrb, Wzb, Urb, Uzb};
  int n4s[6] = {BATCH * ISZ / 4, BATCH * HSZ / 4,
                HSZ * ISZ / 4, HSZ * ISZ / 4,
                HSZ * HSZ / 4, HSZ * HSZ / 4};
  int cum = 0;
  for (int i = 0; i < 6; ++i) {
    ca.src[i] = srcs[i];
    ca.dst[i] = dsts[i];
    ca.cum[i] = cum;
    cum += n4s[i];
  }
  ca.cum[6] = cum;
  cvt_all_kernel<<<(cum + 255) / 256, 256, 0, stream>>>(ca, cum);

  dim3 gridA(HSZ / 128, BATCH / 128, 2);   // z=0: Wh/Uh cvt plane; z=1: merged R+Z gemm
  gate_rz<<<gridA, 256, 0, stream>>>(xb, hb, Wrb, Urb, Wzb, Uzb, br, bz,
                                     Wh, Uh, Whb, Uhb, rhb, Zb);

  dim3 gridB(HSZ / 128, BATCH / 128, 1);   // 512 blocks: 16 col-panels x 32 row-panels
  gate_h<<<gridB, 256, 0, stream>>>(xb, rhb, Whb, Uhb, bh, Zb, hprev, out);
}

// Round 6
// 324.691 us; speedup vs baseline: 1.0963x; 1.0483x over previous
//
#include <hip/hip_runtime.h>

#define BATCH 4096
#define ISZ   1024
#define HSZ   2048

typedef __bf16 bf16x8 __attribute__((ext_vector_type(8)));
typedef float  f32x4  __attribute__((ext_vector_type(4)));

// ---------- fp32 <-> bf16 ----------
__device__ __forceinline__ unsigned short f2bf(float f) {
  unsigned u = __builtin_bit_cast(unsigned, f);
  u += 0x7fffu + ((u >> 16) & 1u);
  return (unsigned short)(u >> 16);
}
__device__ __forceinline__ float bf2f(unsigned short s) {
  unsigned u = ((unsigned)s) << 16;
  return __builtin_bit_cast(float, u);
}

// ---------- cvt1: the 6 tensors gate_rz depends on ----------
// total float4 = (BATCH*ISZ + BATCH*HSZ + 2*HSZ*ISZ + 2*HSZ*HSZ)/4
//              = 6,291,456 = 2048 blocks * 256 threads * 12 iters (exact)
#define CVT_BLOCKS 2048
#define CVT_SPAN   (CVT_BLOCKS * 256)   // 524288
#define CVT_ITERS  12

struct CvtArgs {
  const float* src[6];
  unsigned short* dst[6];
  int cum[7];   // prefix sums of float4 counts
};

__global__ __launch_bounds__(256) void cvt_all_kernel(CvtArgs a) {
  const int tid = blockIdx.x * 256 + threadIdx.x;   // 0..524287
#pragma unroll
  for (int k = 0; k < CVT_ITERS; ++k) {
    int i = tid + k * CVT_SPAN;
    int s = 0;
#pragma unroll
    for (int q = 0; q < 5; ++q) s += (i >= a.cum[q + 1]) ? 1 : 0;
    int off = i - a.cum[s];
    float4 f = ((const float4*)a.src[s])[off];
    ushort4 o;
    o.x = f2bf(f.x); o.y = f2bf(f.y); o.z = f2bf(f.z); o.w = f2bf(f.w);
    ((ushort4*)a.dst[s])[off] = o;
  }
}

// ---------- staging: BK=64, XOR-8 swizzled LDS (conflict-free, verified) ----------
// 128-row tile, 256-thread block: 1024 16-B chunks, 4/thread.
__device__ __forceinline__ void stage_tile64(const unsigned short* __restrict__ g, int ldK,
                                             int tileRow, int k0, char* lds, int t) {
  char* l0 = lds + ((t >> 6) << 10);  // wave-uniform base
#pragma unroll
  for (int k = 0; k < 4; ++k) {
    int linear = t + k * 256;        // chunk id, 0..1023
    int row = linear >> 3;           // 0..127
    int cs  = linear & 7;
    int c   = cs ^ (row & 7);        // XOR swizzle on global side
    const unsigned short* gp = g + (size_t)(tileRow + row) * ldK + (k0 + c * 8);
    __builtin_amdgcn_global_load_lds((const __attribute__((address_space(1))) void*)gp,
                                     (__attribute__((address_space(3))) void*)(l0 + k * 4096),
                                     16, 0, 0);
  }
}

// 128-row tile, 512-thread block: 1024 chunks, 2/thread.
__device__ __forceinline__ void stage_tile64_w8(const unsigned short* __restrict__ g, int ldK,
                                                int tileRow, int k0, char* lds, int t) {
  char* l0 = lds + ((t >> 6) << 10);  // wave-uniform base (wid*1024)
#pragma unroll
  for (int k = 0; k < 2; ++k) {
    int linear = t + k * 512;        // chunk id, 0..1023
    int row = linear >> 3;
    int cs  = linear & 7;
    int c   = cs ^ (row & 7);
    const unsigned short* gp = g + (size_t)(tileRow + row) * ldK + (k0 + c * 8);
    __builtin_amdgcn_global_load_lds((const __attribute__((address_space(1))) void*)gp,
                                     (__attribute__((address_space(3))) void*)(l0 + k * 8192),
                                     16, 0, 0);
  }
}

// ---------- dual-B 128x(2x128) GEMM segment, 4 waves (merged R+Z; verified 966 TF) ----------
__device__ __forceinline__ void gemm_seg_rz(const unsigned short* __restrict__ A,
                                            const unsigned short* __restrict__ Br,
                                            const unsigned short* __restrict__ Bz,
                                            int K, int rowBase, int colBase,
                                            char* ldsA, char* ldsBr, char* ldsBz,
                                            f32x4 (&accR)[4][4], f32x4 (&accZ)[4][4], int t) {
  const int lane = t & 63;
  const int wid  = t >> 6;
  const int wm   = wid >> 1, wn = wid & 1;
  const int lrow = lane & 15;
  const int quad = lane >> 4;
  const int r7   = lrow & 7;
  for (int k0 = 0; k0 < K; k0 += 64) {
    stage_tile64(A,  K, rowBase, k0, ldsA,  t);
    stage_tile64(Br, K, colBase, k0, ldsBr, t);
    stage_tile64(Bz, K, colBase, k0, ldsBz, t);
    __syncthreads();
#pragma unroll
    for (int kk = 0; kk < 2; ++kk) {
      const int swz = (((kk << 2) | quad) ^ r7) * 16;
      bf16x8 af[4], bfr[4];
#pragma unroll
      for (int i = 0; i < 4; ++i)
        af[i] = *(const bf16x8*)(ldsA + (wm * 64 + i * 16 + lrow) * 128 + swz);
#pragma unroll
      for (int j = 0; j < 4; ++j)
        bfr[j] = *(const bf16x8*)(ldsBr + (wn * 64 + j * 16 + lrow) * 128 + swz);
#pragma unroll
      for (int i = 0; i < 4; ++i)
#pragma unroll
        for (int j = 0; j < 4; ++j)
          accR[i][j] = __builtin_amdgcn_mfma_f32_16x16x32_bf16(af[i], bfr[j], accR[i][j], 0, 0, 0);
#pragma unroll
      for (int j = 0; j < 4; ++j)
        bfr[j] = *(const bf16x8*)(ldsBz + (wn * 64 + j * 16 + lrow) * 128 + swz);
#pragma unroll
      for (int i = 0; i < 4; ++i)
#pragma unroll
        for (int j = 0; j < 4; ++j)
          accZ[i][j] = __builtin_amdgcn_mfma_f32_16x16x32_bf16(af[i], bfr[j], accZ[i][j], 0, 0, 0);
    }
    __syncthreads();
  }
}

// ---------- 128x128 GEMM segment, 8 waves (gate_h; wave tile 64x32) ----------
__device__ __forceinline__ void gemm_seg8(const unsigned short* __restrict__ A,
                                          const unsigned short* __restrict__ W,
                                          int K, int rowBase, int colBase,
                                          char* ldsA, char* ldsB,
                                          f32x4 (&acc)[4][2], int t) {
  const int lane = t & 63;
  const int wid  = t >> 6;          // 0..7
  const int wm   = wid >> 2;        // 0..1  (row half)
  const int wn   = wid & 3;        // 0..3  (col quarter)
  const int lrow = lane & 15;
  const int quad = lane >> 4;
  const int r7   = lrow & 7;
  for (int k0 = 0; k0 < K; k0 += 64) {
    stage_tile64_w8(A, K, rowBase, k0, ldsA, t);
    stage_tile64_w8(W, K, colBase, k0, ldsB, t);
    __syncthreads();
#pragma unroll
    for (int kk = 0; kk < 2; ++kk) {
      const int swz = (((kk << 2) | quad) ^ r7) * 16;
      bf16x8 af[4], bfr[2];
#pragma unroll
      for (int i = 0; i < 4; ++i)
        af[i]  = *(const bf16x8*)(ldsA + (wm * 64 + i * 16 + lrow) * 128 + swz);
#pragma unroll
      for (int j = 0; j < 2; ++j)
        bfr[j] = *(const bf16x8*)(ldsB + (wn * 32 + j * 16 + lrow) * 128 + swz);
#pragma unroll
      for (int i = 0; i < 4; ++i)
#pragma unroll
        for (int j = 0; j < 2; ++j)
          acc[i][j] = __builtin_amdgcn_mfma_f32_16x16x32_bf16(af[i], bfr[j], acc[i][j], 0, 0, 0);
    }
    __syncthreads();
  }
}

__device__ __forceinline__ float fast_sigmoid(float v) {
  return 1.0f / (1.0f + __expf(-v));
}
__device__ __forceinline__ float fast_tanh(float v) {
  float e = __expf(2.0f * v);
  return 1.0f - 2.0f / (e + 1.0f);   // safe at +/-inf
}

// ---------- Kernel A: z==0 plane converts Wh/Uh (overlapped); z==1 merged R+Z ----------
__global__ __launch_bounds__(256, 2) void gate_rz(
    const unsigned short* __restrict__ xb, const unsigned short* __restrict__ hb,
    const unsigned short* __restrict__ Wr, const unsigned short* __restrict__ Ur,
    const unsigned short* __restrict__ Wz, const unsigned short* __restrict__ Uz,
    const float* __restrict__ br, const float* __restrict__ bz,
    const float* __restrict__ Wh32, const float* __restrict__ Uh32,
    unsigned short* __restrict__ Whb, unsigned short* __restrict__ Uhb,
    unsigned short* __restrict__ rh, unsigned short* __restrict__ Zbuf) {
  __shared__ char lds[49152];
  const int t = threadIdx.x;

  if (blockIdx.z == 0) {
    // dispatched first (z-major last): converts Wh+Uh during gate_rz's first wave
    const int NW = (HSZ * ISZ) / 4;          // 524288 float4 in Wh
    const int NU = (HSZ * HSZ) / 4;          // 1048576 float4 in Uh
    int tid = (blockIdx.x + (blockIdx.y << 4)) * 256 + t;   // 0..131071
#pragma unroll 4
    for (int i = tid; i < NW + NU; i += 512 * 256) {
      const float4* s4 = (i < NW) ? (const float4*)Wh32 + i
                                  : (const float4*)Uh32 + (i - NW);
      ushort4* d4 = (i < NW) ? (ushort4*)Whb + i
                             : (ushort4*)Uhb + (i - NW);
      float4 f = *s4;
      ushort4 o;
      o.x = f2bf(f.x); o.y = f2bf(f.y); o.z = f2bf(f.z); o.w = f2bf(f.w);
      *d4 = o;
    }
    return;
  }

  char* ldsA  = lds;
  char* ldsBr = lds + 16384;
  char* ldsBz = lds + 32768;

  // weight-stationary XCD swizzle over the 512 merged blocks:
  // each XCD owns 2 col-panels -> Wr/Wz/Ur/Uz panel set = 3 MiB, L2-resident.
  int lin = blockIdx.x + (blockIdx.y << 4);
  int xcd = lin & 7, s = lin >> 3;
  int bx = xcd * 2 + (s & 1);
  int by = s >> 1;                  // 0..31

  const int rowBase = by * 128;
  const int colBase = bx * 128;

  f32x4 accR[4][4], accZ[4][4];
#pragma unroll
  for (int i = 0; i < 4; ++i)
#pragma unroll
    for (int j = 0; j < 4; ++j) {
      accR[i][j] = (f32x4){0.f, 0.f, 0.f, 0.f};
      accZ[i][j] = (f32x4){0.f, 0.f, 0.f, 0.f};
    }

  gemm_seg_rz(xb, Wr, Wz, ISZ, rowBase, colBase, ldsA, ldsBr, ldsBz, accR, accZ, t);
  gemm_seg_rz(hb, Ur, Uz, HSZ, rowBase, colBase, ldsA, ldsBr, ldsBz, accR, accZ, t);

  const int lane = t & 63, wid = t >> 6;
  const int wm = wid >> 1, wn = wid & 1, lrow = lane & 15, quad = lane >> 4;
#pragma unroll
  for (int i = 0; i < 4; ++i) {
#pragma unroll
    for (int j = 0; j < 4; ++j) {
      int col = colBase + wn * 64 + j * 16 + lrow;
      float bvr = br[col];
      float bvz = bz[col];
#pragma unroll
      for (int r = 0; r < 4; ++r) {
        int row = rowBase + wm * 64 + i * 16 + quad * 4 + r;
        int idx = row * HSZ + col;
        float hv = bf2f(hb[idx]);
        float sr = fast_sigmoid(accR[i][j][r] + bvr);
        float sz = fast_sigmoid(accZ[i][j][r] + bvz);
        rh[idx]   = f2bf(sr * hv);
        Zbuf[idx] = f2bf(sz);
      }
    }
  }
}

// ---------- Kernel B: 128x128 tile, 512 threads (8 waves), 16 waves/CU ----------
__global__ __launch_bounds__(512, 4) void gate_h(
    const unsigned short* __restrict__ xb, const unsigned short* __restrict__ rhb,
    const unsigned short* __restrict__ Wh, const unsigned short* __restrict__ Uh,
    const float* __restrict__ bh, const unsigned short* __restrict__ Zbuf,
    const float* __restrict__ hprev, float* __restrict__ out) {
  __shared__ char lds[32768];
  char* ldsA = lds;
  char* ldsB = lds + 16384;
  const int t = threadIdx.x;

  // weight-stationary XCD swizzle: each XCD owns 2 column-panels (grid 16x32)
  int lin = blockIdx.x + (blockIdx.y << 4);
  int xcd = lin & 7, s = lin >> 3;
  int bx = xcd * 2 + (s & 1);
  int by = s >> 1;

  const int rowBase = by * 128;
  const int colBase = bx * 128;

  f32x4 acc[4][2];
#pragma unroll
  for (int i = 0; i < 4; ++i)
#pragma unroll
    for (int j = 0; j < 2; ++j)
      acc[i][j] = (f32x4){0.f, 0.f, 0.f, 0.f};

  gemm_seg8(xb, Wh, ISZ, rowBase, colBase, ldsA, ldsB, acc, t);
  gemm_seg8(rhb, Uh, HSZ, rowBase, colBase, ldsA, ldsB, acc, t);

  const int lane = t & 63, wid = t >> 6;
  const int wm = wid >> 2, wn = wid & 3, lrow = lane & 15, quad = lane >> 4;
#pragma unroll
  for (int i = 0; i < 4; ++i) {
#pragma unroll
    for (int j = 0; j < 2; ++j) {
      int col = colBase + wn * 32 + j * 16 + lrow;
      float bv = bh[col];
#pragma unroll
      for (int r = 0; r < 4; ++r) {
        int row = rowBase + wm * 64 + i * 16 + quad * 4 + r;
        float hp = fast_tanh(acc[i][j][r] + bv);
        int idx = row * HSZ + col;
        float z = bf2f(Zbuf[idx]);
        float h = hprev[idx];
        out[idx] = h + z * (hp - h);
      }
    }
  }
}

// ---------- host ----------
extern "C" void kernel_launch(void* const* d_in, const int* in_sizes, int n_in,
                              void* d_out, int out_size, void* d_ws, size_t ws_size,
                              hipStream_t stream) {
  (void)in_sizes; (void)n_in; (void)out_size; (void)ws_size;
  const float* x     = (const float*)d_in[0];
  const float* hprev = (const float*)d_in[1];
  const float* Wh    = (const float*)d_in[2];
  const float* Wz    = (const float*)d_in[3];
  const float* Wr    = (const float*)d_in[4];
  const float* Uh    = (const float*)d_in[5];
  const float* Uz    = (const float*)d_in[6];
  const float* Ur    = (const float*)d_in[7];
  const float* bh    = (const float*)d_in[8];
  const float* bz    = (const float*)d_in[9];
  const float* br    = (const float*)d_in[10];
  float* out = (float*)d_out;

  char* ws = (char*)d_ws;
  size_t off = 0;
  auto alloc = [&](size_t bytes) { char* p = ws + off; off += bytes; return p; };
  unsigned short* xb  = (unsigned short*)alloc((size_t)BATCH * ISZ * 2);
  unsigned short* hb  = (unsigned short*)alloc((size_t)BATCH * HSZ * 2);
  unsigned short* Wrb = (unsigned short*)alloc((size_t)HSZ * ISZ * 2);
  unsigned short* Wzb = (unsigned short*)alloc((size_t)HSZ * ISZ * 2);
  unsigned short* Whb = (unsigned short*)alloc((size_t)HSZ * ISZ * 2);
  unsigned short* Urb = (unsigned short*)alloc((size_t)HSZ * HSZ * 2);
  unsigned short* Uzb = (unsigned short*)alloc((size_t)HSZ * HSZ * 2);
  unsigned short* Uhb = (unsigned short*)alloc((size_t)HSZ * HSZ * 2);
  unsigned short* rhb = (unsigned short*)alloc((size_t)BATCH * HSZ * 2);
  unsigned short* Zb  = (unsigned short*)alloc((size_t)BATCH * HSZ * 2);

  // cvt1: only what gate_rz needs (Wh/Uh are converted inside gate_rz's z==0 plane)
  CvtArgs ca;
  const float* srcs[6]      = {x, hprev, Wr, Wz, Ur, Uz};
  unsigned short* dsts[6]   = {xb, hb, Wrb, Wzb, Urb, Uzb};
  int n4s[6] = {BATCH * ISZ / 4, BATCH * HSZ / 4,
                HSZ * ISZ / 4, HSZ * ISZ / 4,
                HSZ * HSZ / 4, HSZ * HSZ / 4};
  int cum = 0;
  for (int i = 0; i < 6; ++i) {
    ca.src[i] = srcs[i];
    ca.dst[i] = dsts[i];
    ca.cum[i] = cum;
    cum += n4s[i];
  }
  ca.cum[6] = cum;   // == CVT_BLOCKS*256*CVT_ITERS = 6291456 (exact, no remainder)
  cvt_all_kernel<<<CVT_BLOCKS, 256, 0, stream>>>(ca);

  dim3 gridA(HSZ / 128, BATCH / 128, 2);   // z=0: Wh/Uh cvt plane; z=1: merged R+Z gemm
  gate_rz<<<gridA, 256, 0, stream>>>(xb, hb, Wrb, Urb, Wzb, Uzb, br, bz,
                                     Wh, Uh, Whb, Uhb, rhb, Zb);

  dim3 gridB(HSZ / 128, BATCH / 128, 1);
  gate_h<<<gridB, 512, 0, stream>>>(xb, rhb, Whb, Uhb, bh, Zb, hprev, out);
}